// Round 12
// baseline (119.194 us; speedup 1.0000x reference)
//
#include <hip/hip_runtime.h>
#include <math.h>

constexpr int NB = 8192;   // batch
constexpr int ND = 1024;   // dim
constexpr int NK = 30;     // negatives
constexpr int RS = ND / 4; // row stride in ints (256)
constexpr int TASKS_PER_CHUNK = NB / 4;   // 2048 (4 rows per task)

#if defined(__has_builtin)
#  if __has_builtin(__builtin_amdgcn_sdot4)
#    define HAVE_SDOT4 1
#  endif
#endif
#ifndef HAVE_SDOT4
#  define HAVE_SDOT4 0
#endif

__device__ __forceinline__ int SDOT4(int a, int b, int acc) {
#if HAVE_SDOT4
    return __builtin_amdgcn_sdot4(a, b, acc, false);
#else
    return acc + (int)(signed char)(a)        * (int)(signed char)(b)
               + (int)(signed char)(a >> 8)   * (int)(signed char)(b >> 8)
               + (int)(signed char)(a >> 16)  * (int)(signed char)(b >> 16)
               + (int)(a >> 24)               * (int)(b >> 24);
#endif
}

__device__ __forceinline__ int pack4_i8(float a, float b, float c, float d) {
    int x0 = (int)rintf(a), x1 = (int)rintf(b), x2 = (int)rintf(c), x3 = (int)rintf(d);
    return (x0 & 255) | ((x1 & 255) << 8) | ((x2 & 255) << 16) | (x3 << 24);
}

// physical XCD id (0..7) — HW-verified readable on gfx950 (learn_hip m09)
__device__ __forceinline__ int xcc_id() {
    int x;
    asm volatile("s_getreg_b32 %0, hwreg(HW_REG_XCC_ID)" : "=s"(x));
    return x & 7;
}

// ---------------------------------------------------------------------------
// Kernel 1: normalize rows of [z_i; z_j] -> int8 pool [2B, D], scale 127.
// Also zero-inits logits, the 8 work counters, and out[0] (stream-ordered
// before the atomics in later kernels). One wave per row, 4 waves/block.
// ---------------------------------------------------------------------------
__global__ void normalize_i8_kernel(const float* __restrict__ zi,
                                    const float* __restrict__ zj,
                                    int* __restrict__ pool,
                                    int* __restrict__ logits,
                                    int* __restrict__ ctr,
                                    float* __restrict__ out) {
    if (blockIdx.x == 0) {
        if (threadIdx.x == 0) out[0] = 0.f;
        if (threadIdx.x < 128) ctr[threadIdx.x] = 0;   // 8 counters, 64B-padded
    }
    if (threadIdx.x < 64)
        logits[blockIdx.x * 64 + threadIdx.x] = 0;

    int row  = blockIdx.x * 4 + (threadIdx.x >> 6);
    int lane = threadIdx.x & 63;
    const float* src = (row < NB) ? (zi + (size_t)row * ND)
                                  : (zj + (size_t)(row - NB) * ND);
    float v[16];
    float s = 0.f;
#pragma unroll
    for (int seg = 0; seg < 4; ++seg) {
        float4 t = *reinterpret_cast<const float4*>(src + lane * 16 + seg * 4);
        v[seg * 4 + 0] = t.x; v[seg * 4 + 1] = t.y;
        v[seg * 4 + 2] = t.z; v[seg * 4 + 3] = t.w;
        s += t.x * t.x + t.y * t.y + t.z * t.z + t.w * t.w;
    }
#pragma unroll
    for (int off = 32; off >= 1; off >>= 1)
        s += __shfl_xor(s, off, 64);
    float inv = 127.f / fmaxf(sqrtf(s), 1e-12f);

    int4 w;
    w.x = pack4_i8(v[0]*inv,  v[1]*inv,  v[2]*inv,  v[3]*inv);
    w.y = pack4_i8(v[4]*inv,  v[5]*inv,  v[6]*inv,  v[7]*inv);
    w.z = pack4_i8(v[8]*inv,  v[9]*inv,  v[10]*inv, v[11]*inv);
    w.w = pack4_i8(v[12]*inv, v[13]*inv, v[14]*inv, v[15]*inv);
    *reinterpret_cast<int4*>(pool + (size_t)row * RS + lane * 4) = w;
}

// ---------------------------------------------------------------------------
// Kernel 2: persistent, physically XCD-affine partial dots.
// 2048 co-resident blocks self-schedule via 8 per-chunk counters; each block
// reads its REAL XCD id and drains that chunk's tasks (4 rows each), then
// steals from other chunks (completeness never depends on dispatch mapping).
// Per task: 32 slots (0 = positive row+NB, 1..30 = negatives, 31 = pad);
// g = lane>>3 slot-in-round, p = lane&7 16B fragment of the 128B chunk.
// Exact int partials folded into logits[row][slot] via device atomics
// (associative -> bitwise deterministic).
// ---------------------------------------------------------------------------
__global__ void loss_chunk_kernel(const int* __restrict__ pool,
                                  const int* __restrict__ neg_idx,
                                  int* __restrict__ logits,
                                  int* __restrict__ ctr) {
    __shared__ int task_s;
    int wave = threadIdx.x >> 6;
    int lane = threadIdx.x & 63;
    int g    = lane >> 3;
    int p    = lane & 7;
    int myx  = xcc_id();

    for (int cc = 0; cc < 8; ++cc) {
        int c = (myx + cc) & 7;
        const int* cbase = pool + c * 32 + p * 4;

        while (true) {
            __syncthreads();
            if (threadIdx.x == 0)
                task_s = atomicAdd(&ctr[c * 16], 1);
            __syncthreads();
            int t = task_s;
            if (t >= TASKS_PER_CHUNK) break;

            int row = t * 4 + wave;

            int myidx = (lane < NK) ? neg_idx[row * NK + lane] : 0;
            int4 a4 = *reinterpret_cast<const int4*>(cbase + (size_t)row * RS);

            int4 b4[4];
#pragma unroll
            for (int tt = 0; tt < 4; ++tt) {
                int s = tt * 8 + g;
                int r = (s == 0) ? (row + NB)
                      : (s < 31) ? __shfl(myidx, s - 1, 64)
                                 : 0;              // pad slot (masked in lse)
                b4[tt] = *reinterpret_cast<const int4*>(cbase + (size_t)r * RS);
            }

            int d0 = 0, d1 = 0, d2 = 0, d3 = 0;
            d0 = SDOT4(a4.x, b4[0].x, d0); d0 = SDOT4(a4.y, b4[0].y, d0);
            d0 = SDOT4(a4.z, b4[0].z, d0); d0 = SDOT4(a4.w, b4[0].w, d0);
            d1 = SDOT4(a4.x, b4[1].x, d1); d1 = SDOT4(a4.y, b4[1].y, d1);
            d1 = SDOT4(a4.z, b4[1].z, d1); d1 = SDOT4(a4.w, b4[1].w, d1);
            d2 = SDOT4(a4.x, b4[2].x, d2); d2 = SDOT4(a4.y, b4[2].y, d2);
            d2 = SDOT4(a4.z, b4[2].z, d2); d2 = SDOT4(a4.w, b4[2].w, d2);
            d3 = SDOT4(a4.x, b4[3].x, d3); d3 = SDOT4(a4.y, b4[3].y, d3);
            d3 = SDOT4(a4.z, b4[3].z, d3); d3 = SDOT4(a4.w, b4[3].w, d3);

#pragma unroll
            for (int off = 1; off <= 4; off <<= 1) {
                d0 += __shfl_xor(d0, off, 64);
                d1 += __shfl_xor(d1, off, 64);
                d2 += __shfl_xor(d2, off, 64);
                d3 += __shfl_xor(d3, off, 64);
            }

            if (p < 4) {
                int val = (p == 0) ? d0 : (p == 1) ? d1 : (p == 2) ? d2 : d3;
                atomicAdd(&logits[row * 32 + p * 8 + g], val);
            }
        }
    }
}

// ---------------------------------------------------------------------------
// Kernel 3: logsumexp + final mean fold. 2 rows per wave (32 lanes each),
// 8 rows per block; one float atomicAdd to out[0] per block.
// ---------------------------------------------------------------------------
__global__ void lse_kernel(const int* __restrict__ logits,
                           const float* __restrict__ temp_ptr,
                           float* __restrict__ out) {
    int wave = threadIdx.x >> 6;
    int lane = threadIdx.x & 63;
    int slot = lane & 31;
    int row  = blockIdx.x * 8 + wave * 2 + (lane >> 5);

    float inv_t = 1.f / (127.f * 127.f * temp_ptr[0]);

    float l = (slot < 31) ? logits[row * 32 + slot] * inv_t : -1e30f;

    float m = l;
#pragma unroll
    for (int off = 1; off <= 16; off <<= 1)
        m = fmaxf(m, __shfl_xor(m, off, 64));
    float e = __expf(l - m);
#pragma unroll
    for (int off = 1; off <= 16; off <<= 1)
        e += __shfl_xor(e, off, 64);

    float l0    = __shfl(l, lane & 32, 64);     // slot 0 of own half
    float loss  = (m + logf(e)) - l0;
    float loss2 = __shfl(loss, 32, 64);         // other half's loss

    __shared__ float red[4];
    if (lane == 0) red[wave] = loss + loss2;
    __syncthreads();
    if (threadIdx.x == 0)
        atomicAdd(out, (red[0] + red[1] + red[2] + red[3]) * (1.f / (float)NB));
}

// ---------------------------------------------------------------------------
// f32 fallback (only if ws too small for pool + logits + counters)
// ---------------------------------------------------------------------------
__global__ void norms_kernel(const float* __restrict__ zi,
                             const float* __restrict__ zj,
                             float* __restrict__ inv_norm) {
    int row  = blockIdx.x * 4 + (threadIdx.x >> 6);
    int lane = threadIdx.x & 63;
    if (row >= 2 * NB) return;
    const float* src = (row < NB) ? (zi + (size_t)row * ND)
                                  : (zj + (size_t)(row - NB) * ND);
    float s = 0.f;
#pragma unroll
    for (int seg = 0; seg < 4; ++seg) {
        float4 v = *reinterpret_cast<const float4*>(src + seg * 256 + lane * 4);
        s += v.x*v.x + v.y*v.y + v.z*v.z + v.w*v.w;
    }
#pragma unroll
    for (int off = 32; off >= 1; off >>= 1)
        s += __shfl_xor(s, off, 64);
    if (lane == 0)
        inv_norm[row] = 1.f / fmaxf(sqrtf(s), 1e-12f);
}

__global__ void loss_kernel_f32(const float* __restrict__ zi,
                                const float* __restrict__ zj,
                                const int*   __restrict__ neg_idx,
                                const float* __restrict__ temp_ptr,
                                const float* __restrict__ inv_norm,
                                float* __restrict__ partial) {
    int wave = threadIdx.x >> 6;
    int lane = threadIdx.x & 63;
    int row  = blockIdx.x * 4 + wave;
    float inv_t = 1.f / temp_ptr[0];
    const float* a = zi + (size_t)row * ND;
    float4 av[4];
#pragma unroll
    for (int seg = 0; seg < 4; ++seg)
        av[seg] = *reinterpret_cast<const float4*>(a + seg * 256 + lane * 4);
    float inv_a = inv_norm[row];
    float m = -INFINITY, ssum = 0.f, logit0 = 0.f;
    for (int k = -1; k < NK; ++k) {
        int r = (k < 0) ? (row + NB) : neg_idx[row * NK + k];
        const float* bp = (r < NB) ? (zi + (size_t)r * ND)
                                   : (zj + (size_t)(r - NB) * ND);
        float inv_b = inv_norm[r];
        float dot = 0.f;
#pragma unroll
        for (int seg = 0; seg < 4; ++seg) {
            float4 bv = *reinterpret_cast<const float4*>(bp + seg * 256 + lane * 4);
            dot += av[seg].x*bv.x + av[seg].y*bv.y + av[seg].z*bv.z + av[seg].w*bv.w;
        }
#pragma unroll
        for (int off = 32; off >= 1; off >>= 1)
            dot += __shfl_xor(dot, off, 64);
        float logit = dot * inv_a * inv_b * inv_t;
        if (k < 0) logit0 = logit;
        if (logit > m) { ssum = ssum * __expf(m - logit) + 1.f; m = logit; }
        else           { ssum += __expf(logit - m); }
    }
    float loss = (m + logf(ssum)) - logit0;
    __shared__ float red[4];
    if (lane == 0) red[wave] = loss;
    __syncthreads();
    if (threadIdx.x == 0)
        partial[blockIdx.x] = red[0] + red[1] + red[2] + red[3];
}

__global__ void reduce_kernel(const float* __restrict__ partial, int n,
                              float* __restrict__ out) {
    float s = 0.f;
    for (int i = threadIdx.x; i < n; i += 256) s += partial[i];
#pragma unroll
    for (int off = 32; off >= 1; off >>= 1)
        s += __shfl_xor(s, off, 64);
    __shared__ float lds[4];
    int wave = threadIdx.x >> 6, lane = threadIdx.x & 63;
    if (lane == 0) lds[wave] = s;
    __syncthreads();
    if (threadIdx.x == 0)
        out[0] = (lds[0] + lds[1] + lds[2] + lds[3]) * (1.f / (float)NB);
}

extern "C" void kernel_launch(void* const* d_in, const int* in_sizes, int n_in,
                              void* d_out, int out_size, void* d_ws, size_t ws_size,
                              hipStream_t stream) {
    const float* zi      = (const float*)d_in[0];
    const float* zj      = (const float*)d_in[1];
    const float* temp    = (const float*)d_in[2];
    const int*   neg_idx = (const int*)d_in[3];
    float* out = (float*)d_out;

    const size_t pool_bytes   = (size_t)2 * NB * ND;                // 16 MiB
    const size_t logits_bytes = (size_t)NB * 32 * sizeof(int);      //  1 MiB
    const size_t ctr_bytes    = 128 * sizeof(int);                  // 8 ctrs, padded

    if (ws_size >= pool_bytes + logits_bytes + ctr_bytes) {
        int* pool   = (int*)d_ws;
        int* logits = (int*)((char*)d_ws + pool_bytes);
        int* ctr    = (int*)((char*)d_ws + pool_bytes + logits_bytes);

        normalize_i8_kernel<<<(2 * NB) / 4, 256, 0, stream>>>(zi, zj, pool,
                                                              logits, ctr, out);
        loss_chunk_kernel<<<2048, 256, 0, stream>>>(pool, neg_idx, logits, ctr);
        lse_kernel<<<NB / 8, 256, 0, stream>>>(logits, temp, out);
    } else {
        float* inv_norm = (float*)d_ws;
        float* partial  = inv_norm + 2 * NB;

        norms_kernel<<<(2 * NB) / 4, 256, 0, stream>>>(zi, zj, inv_norm);
        loss_kernel_f32<<<NB / 4, 256, 0, stream>>>(zi, zj, neg_idx, temp,
                                                    inv_norm, partial);
        reduce_kernel<<<1, 256, 0, stream>>>(partial, NB / 4, out);
    }
}

// Round 13
// 113.475 us; speedup vs baseline: 1.0504x; 1.0504x over previous
//
#include <hip/hip_runtime.h>
#include <math.h>

constexpr int NB = 8192;   // batch
constexpr int ND = 1024;   // dim
constexpr int NK = 30;     // negatives
constexpr int RS = ND / 4; // row stride in ints (256)
constexpr int TPC   = NB / 4;  // tasks per chunk (4 rows per task) = 2048
constexpr int BATCH = 8;       // tasks claimed per atomic grab

#if defined(__has_builtin)
#  if __has_builtin(__builtin_amdgcn_sdot4)
#    define HAVE_SDOT4 1
#  endif
#endif
#ifndef HAVE_SDOT4
#  define HAVE_SDOT4 0
#endif

__device__ __forceinline__ int SDOT4(int a, int b, int acc) {
#if HAVE_SDOT4
    return __builtin_amdgcn_sdot4(a, b, acc, false);
#else
    return acc + (int)(signed char)(a)        * (int)(signed char)(b)
               + (int)(signed char)(a >> 8)   * (int)(signed char)(b >> 8)
               + (int)(signed char)(a >> 16)  * (int)(signed char)(b >> 16)
               + (int)(a >> 24)               * (int)(b >> 24);
#endif
}

__device__ __forceinline__ int pack4_i8(float a, float b, float c, float d) {
    int x0 = (int)rintf(a), x1 = (int)rintf(b), x2 = (int)rintf(c), x3 = (int)rintf(d);
    return (x0 & 255) | ((x1 & 255) << 8) | ((x2 & 255) << 16) | (x3 << 24);
}

// physical XCD id (0..7) — HW-verified readable on gfx950 (learn_hip m09; r12 correct)
__device__ __forceinline__ int xcc_id() {
    int x;
    asm volatile("s_getreg_b32 %0, hwreg(HW_REG_XCC_ID)" : "=s"(x));
    return x & 7;
}

// ---------------------------------------------------------------------------
// Kernel 1: normalize rows of [z_i; z_j] -> int8 pool [2B, D], scale 127.
// Also zero-inits logits, the 8 work counters, and out[0] (stream-ordered
// before the atomics in later kernels). One wave per row, 4 waves/block.
// ---------------------------------------------------------------------------
__global__ void normalize_i8_kernel(const float* __restrict__ zi,
                                    const float* __restrict__ zj,
                                    int* __restrict__ pool,
                                    int* __restrict__ logits,
                                    int* __restrict__ ctr,
                                    float* __restrict__ out) {
    if (blockIdx.x == 0) {
        if (threadIdx.x == 0) out[0] = 0.f;
        if (threadIdx.x < 128) ctr[threadIdx.x] = 0;   // 8 counters, 64B-padded
    }
    if (threadIdx.x < 64)
        logits[blockIdx.x * 64 + threadIdx.x] = 0;

    int row  = blockIdx.x * 4 + (threadIdx.x >> 6);
    int lane = threadIdx.x & 63;
    const float* src = (row < NB) ? (zi + (size_t)row * ND)
                                  : (zj + (size_t)(row - NB) * ND);
    float v[16];
    float s = 0.f;
#pragma unroll
    for (int seg = 0; seg < 4; ++seg) {
        float4 t = *reinterpret_cast<const float4*>(src + lane * 16 + seg * 4);
        v[seg * 4 + 0] = t.x; v[seg * 4 + 1] = t.y;
        v[seg * 4 + 2] = t.z; v[seg * 4 + 3] = t.w;
        s += t.x * t.x + t.y * t.y + t.z * t.z + t.w * t.w;
    }
#pragma unroll
    for (int off = 32; off >= 1; off >>= 1)
        s += __shfl_xor(s, off, 64);
    float inv = 127.f / fmaxf(sqrtf(s), 1e-12f);

    int4 w;
    w.x = pack4_i8(v[0]*inv,  v[1]*inv,  v[2]*inv,  v[3]*inv);
    w.y = pack4_i8(v[4]*inv,  v[5]*inv,  v[6]*inv,  v[7]*inv);
    w.z = pack4_i8(v[8]*inv,  v[9]*inv,  v[10]*inv, v[11]*inv);
    w.w = pack4_i8(v[12]*inv, v[13]*inv, v[14]*inv, v[15]*inv);
    *reinterpret_cast<int4*>(pool + (size_t)row * RS + lane * 4) = w;
}

// ---------------------------------------------------------------------------
// Kernel 2: persistent, physically XCD-affine partial dots (fixed dispenser).
// 2048 co-resident blocks; each reads its REAL XCD id and drains its chunk's
// tasks in batches of 8 (one atomic RMW per batch, barriers only per batch;
// waves process rows sync-free within a batch). Stealing from other chunks is
// guarded by a monotonic-counter peek (plain load) so empty chunks cost no RMW.
// Per task: 4 rows x 128B chunk; 32 slots (0 = positive row+NB, 1..30 =
// negatives, 31 = pad); g = lane>>3 slot-in-round, p = lane&7 16B fragment.
// Exact int partials folded into logits[row][slot] via device atomics.
// ---------------------------------------------------------------------------
__global__ void loss_chunk_kernel(const int* __restrict__ pool,
                                  const int* __restrict__ neg_idx,
                                  int* __restrict__ logits,
                                  int* __restrict__ ctr) {
    __shared__ int task_s;
    int wave = threadIdx.x >> 6;
    int lane = threadIdx.x & 63;
    int g    = lane >> 3;
    int p    = lane & 7;
    int myx  = xcc_id();

    for (int cc = 0; cc < 8; ++cc) {
        int c = (myx + cc) & 7;
        const int* cbase = pool + c * 32 + p * 4;

        // cheap peek before touching a (possibly drained) chunk's counter:
        // counter is monotonic, so peek>=TPC is a safe skip; stale-low reads
        // merely cost one extra harmless RMW.
        if (cc > 0) {
            int v = *(volatile const int*)&ctr[c * 16];
            if (v >= TPC) continue;
        }

        while (true) {
            __syncthreads();
            if (threadIdx.x == 0)
                task_s = atomicAdd(&ctr[c * 16], BATCH);
            __syncthreads();
            int t0 = task_s;
            if (t0 >= TPC) break;
            int tend = t0 + BATCH; if (tend > TPC) tend = TPC;

            for (int t = t0; t < tend; ++t) {
                int row = t * 4 + wave;

                int myidx = (lane < NK) ? neg_idx[row * NK + lane] : 0;
                int4 a4 = *reinterpret_cast<const int4*>(cbase + (size_t)row * RS);

                int4 b4[4];
#pragma unroll
                for (int tt = 0; tt < 4; ++tt) {
                    int s = tt * 8 + g;
                    int r = (s == 0) ? (row + NB)
                          : (s < 31) ? __shfl(myidx, s - 1, 64)
                                     : 0;          // pad slot (masked in lse)
                    b4[tt] = *reinterpret_cast<const int4*>(cbase + (size_t)r * RS);
                }

                int d0 = 0, d1 = 0, d2 = 0, d3 = 0;
                d0 = SDOT4(a4.x, b4[0].x, d0); d0 = SDOT4(a4.y, b4[0].y, d0);
                d0 = SDOT4(a4.z, b4[0].z, d0); d0 = SDOT4(a4.w, b4[0].w, d0);
                d1 = SDOT4(a4.x, b4[1].x, d1); d1 = SDOT4(a4.y, b4[1].y, d1);
                d1 = SDOT4(a4.z, b4[1].z, d1); d1 = SDOT4(a4.w, b4[1].w, d1);
                d2 = SDOT4(a4.x, b4[2].x, d2); d2 = SDOT4(a4.y, b4[2].y, d2);
                d2 = SDOT4(a4.z, b4[2].z, d2); d2 = SDOT4(a4.w, b4[2].w, d2);
                d3 = SDOT4(a4.x, b4[3].x, d3); d3 = SDOT4(a4.y, b4[3].y, d3);
                d3 = SDOT4(a4.z, b4[3].z, d3); d3 = SDOT4(a4.w, b4[3].w, d3);

#pragma unroll
                for (int off = 1; off <= 4; off <<= 1) {
                    d0 += __shfl_xor(d0, off, 64);
                    d1 += __shfl_xor(d1, off, 64);
                    d2 += __shfl_xor(d2, off, 64);
                    d3 += __shfl_xor(d3, off, 64);
                }

                if (p < 4) {
                    int val = (p == 0) ? d0 : (p == 1) ? d1 : (p == 2) ? d2 : d3;
                    atomicAdd(&logits[row * 32 + p * 8 + g], val);
                }
            }
        }
    }
}

// ---------------------------------------------------------------------------
// Kernel 3: logsumexp + final mean fold. 2 rows per wave (32 lanes each),
// 8 rows per block; one float atomicAdd to out[0] per block.
// ---------------------------------------------------------------------------
__global__ void lse_kernel(const int* __restrict__ logits,
                           const float* __restrict__ temp_ptr,
                           float* __restrict__ out) {
    int wave = threadIdx.x >> 6;
    int lane = threadIdx.x & 63;
    int slot = lane & 31;
    int row  = blockIdx.x * 8 + wave * 2 + (lane >> 5);

    float inv_t = 1.f / (127.f * 127.f * temp_ptr[0]);

    float l = (slot < 31) ? logits[row * 32 + slot] * inv_t : -1e30f;

    float m = l;
#pragma unroll
    for (int off = 1; off <= 16; off <<= 1)
        m = fmaxf(m, __shfl_xor(m, off, 64));
    float e = __expf(l - m);
#pragma unroll
    for (int off = 1; off <= 16; off <<= 1)
        e += __shfl_xor(e, off, 64);

    float l0    = __shfl(l, lane & 32, 64);     // slot 0 of own half
    float loss  = (m + logf(e)) - l0;
    float loss2 = __shfl(loss, 32, 64);         // other half's loss

    __shared__ float red[4];
    if (lane == 0) red[wave] = loss + loss2;
    __syncthreads();
    if (threadIdx.x == 0)
        atomicAdd(out, (red[0] + red[1] + red[2] + red[3]) * (1.f / (float)NB));
}

// ---------------------------------------------------------------------------
// f32 fallback (only if ws too small for pool + logits + counters)
// ---------------------------------------------------------------------------
__global__ void norms_kernel(const float* __restrict__ zi,
                             const float* __restrict__ zj,
                             float* __restrict__ inv_norm) {
    int row  = blockIdx.x * 4 + (threadIdx.x >> 6);
    int lane = threadIdx.x & 63;
    if (row >= 2 * NB) return;
    const float* src = (row < NB) ? (zi + (size_t)row * ND)
                                  : (zj + (size_t)(row - NB) * ND);
    float s = 0.f;
#pragma unroll
    for (int seg = 0; seg < 4; ++seg) {
        float4 v = *reinterpret_cast<const float4*>(src + seg * 256 + lane * 4);
        s += v.x*v.x + v.y*v.y + v.z*v.z + v.w*v.w;
    }
#pragma unroll
    for (int off = 32; off >= 1; off >>= 1)
        s += __shfl_xor(s, off, 64);
    if (lane == 0)
        inv_norm[row] = 1.f / fmaxf(sqrtf(s), 1e-12f);
}

__global__ void loss_kernel_f32(const float* __restrict__ zi,
                                const float* __restrict__ zj,
                                const int*   __restrict__ neg_idx,
                                const float* __restrict__ temp_ptr,
                                const float* __restrict__ inv_norm,
                                float* __restrict__ partial) {
    int wave = threadIdx.x >> 6;
    int lane = threadIdx.x & 63;
    int row  = blockIdx.x * 4 + wave;
    float inv_t = 1.f / temp_ptr[0];
    const float* a = zi + (size_t)row * ND;
    float4 av[4];
#pragma unroll
    for (int seg = 0; seg < 4; ++seg)
        av[seg] = *reinterpret_cast<const float4*>(a + seg * 256 + lane * 4);
    float inv_a = inv_norm[row];
    float m = -INFINITY, ssum = 0.f, logit0 = 0.f;
    for (int k = -1; k < NK; ++k) {
        int r = (k < 0) ? (row + NB) : neg_idx[row * NK + k];
        const float* bp = (r < NB) ? (zi + (size_t)r * ND)
                                   : (zj + (size_t)(r - NB) * ND);
        float inv_b = inv_norm[r];
        float dot = 0.f;
#pragma unroll
        for (int seg = 0; seg < 4; ++seg) {
            float4 bv = *reinterpret_cast<const float4*>(bp + seg * 256 + lane * 4);
            dot += av[seg].x*bv.x + av[seg].y*bv.y + av[seg].z*bv.z + av[seg].w*bv.w;
        }
#pragma unroll
        for (int off = 32; off >= 1; off >>= 1)
            dot += __shfl_xor(dot, off, 64);
        float logit = dot * inv_a * inv_b * inv_t;
        if (k < 0) logit0 = logit;
        if (logit > m) { ssum = ssum * __expf(m - logit) + 1.f; m = logit; }
        else           { ssum += __expf(logit - m); }
    }
    float loss = (m + logf(ssum)) - logit0;
    __shared__ float red[4];
    if (lane == 0) red[wave] = loss;
    __syncthreads();
    if (threadIdx.x == 0)
        partial[blockIdx.x] = red[0] + red[1] + red[2] + red[3];
}

__global__ void reduce_kernel(const float* __restrict__ partial, int n,
                              float* __restrict__ out) {
    float s = 0.f;
    for (int i = threadIdx.x; i < n; i += 256) s += partial[i];
#pragma unroll
    for (int off = 32; off >= 1; off >>= 1)
        s += __shfl_xor(s, off, 64);
    __shared__ float lds[4];
    int wave = threadIdx.x >> 6, lane = threadIdx.x & 63;
    if (lane == 0) lds[wave] = s;
    __syncthreads();
    if (threadIdx.x == 0)
        out[0] = (lds[0] + lds[1] + lds[2] + lds[3]) * (1.f / (float)NB);
}

extern "C" void kernel_launch(void* const* d_in, const int* in_sizes, int n_in,
                              void* d_out, int out_size, void* d_ws, size_t ws_size,
                              hipStream_t stream) {
    const float* zi      = (const float*)d_in[0];
    const float* zj      = (const float*)d_in[1];
    const float* temp    = (const float*)d_in[2];
    const int*   neg_idx = (const int*)d_in[3];
    float* out = (float*)d_out;

    const size_t pool_bytes   = (size_t)2 * NB * ND;                // 16 MiB
    const size_t logits_bytes = (size_t)NB * 32 * sizeof(int);      //  1 MiB
    const size_t ctr_bytes    = 128 * sizeof(int);                  // 8 ctrs, padded

    if (ws_size >= pool_bytes + logits_bytes + ctr_bytes) {
        int* pool   = (int*)d_ws;
        int* logits = (int*)((char*)d_ws + pool_bytes);
        int* ctr    = (int*)((char*)d_ws + pool_bytes + logits_bytes);

        normalize_i8_kernel<<<(2 * NB) / 4, 256, 0, stream>>>(zi, zj, pool,
                                                              logits, ctr, out);
        loss_chunk_kernel<<<2048, 256, 0, stream>>>(pool, neg_idx, logits, ctr);
        lse_kernel<<<NB / 8, 256, 0, stream>>>(logits, temp, out);
    } else {
        float* inv_norm = (float*)d_ws;
        float* partial  = inv_norm + 2 * NB;

        norms_kernel<<<(2 * NB) / 4, 256, 0, stream>>>(zi, zj, inv_norm);
        loss_kernel_f32<<<NB / 4, 256, 0, stream>>>(zi, zj, neg_idx, temp,
                                                    inv_norm, partial);
        reduce_kernel<<<1, 256, 0, stream>>>(partial, NB / 4, out);
    }
}

// Round 14
// 109.513 us; speedup vs baseline: 1.0884x; 1.0362x over previous
//
#include <hip/hip_runtime.h>
#include <math.h>

constexpr int NB = 8192;   // batch
constexpr int ND = 1024;   // dim
constexpr int NK = 30;     // negatives
constexpr int RS = ND / 4; // row stride in ints (256)
constexpr int TPC   = NB / 4;  // tasks per chunk (4 rows per task) = 2048
constexpr int BATCH = 8;       // tasks claimed per atomic grab

#if defined(__has_builtin)
#  if __has_builtin(__builtin_amdgcn_sdot4)
#    define HAVE_SDOT4 1
#  endif
#endif
#ifndef HAVE_SDOT4
#  define HAVE_SDOT4 0
#endif

__device__ __forceinline__ int SDOT4(int a, int b, int acc) {
#if HAVE_SDOT4
    return __builtin_amdgcn_sdot4(a, b, acc, false);
#else
    return acc + (int)(signed char)(a)        * (int)(signed char)(b)
               + (int)(signed char)(a >> 8)   * (int)(signed char)(b >> 8)
               + (int)(signed char)(a >> 16)  * (int)(signed char)(b >> 16)
               + (int)(a >> 24)               * (int)(b >> 24);
#endif
}

__device__ __forceinline__ int pack4_i8(float a, float b, float c, float d) {
    int x0 = (int)rintf(a), x1 = (int)rintf(b), x2 = (int)rintf(c), x3 = (int)rintf(d);
    return (x0 & 255) | ((x1 & 255) << 8) | ((x2 & 255) << 16) | (x3 << 24);
}

// physical XCD id (0..7) — HW-verified readable on gfx950 (learn_hip m09)
__device__ __forceinline__ int xcc_id() {
    int x;
    asm volatile("s_getreg_b32 %0, hwreg(HW_REG_XCC_ID)" : "=s"(x));
    return x & 7;
}

// ---------------------------------------------------------------------------
// Pool layout with per-row chunk rotation (L2 channel de-correlation):
// logical chunk c (128B) of row r lives at physical offset ((c + r) & 7)*128.
// Line-address low bits = (c + r) & 7 -> uniform across L2 channels for any
// fixed logical chunk, while chunk c's working set stays 2 MB / XCD-resident.
// ---------------------------------------------------------------------------

// Kernel 1: normalize rows of [z_i; z_j] -> int8 pool (rotated), scale 127.
// Also zero-inits logits, the 8 work counters, and out[0]. One wave per row.
__global__ void normalize_i8_kernel(const float* __restrict__ zi,
                                    const float* __restrict__ zj,
                                    int* __restrict__ pool,
                                    int* __restrict__ logits,
                                    int* __restrict__ ctr,
                                    float* __restrict__ out) {
    if (blockIdx.x == 0) {
        if (threadIdx.x == 0) out[0] = 0.f;
        if (threadIdx.x < 128) ctr[threadIdx.x] = 0;   // 8 counters, 64B-padded
    }
    if (threadIdx.x < 64)
        logits[blockIdx.x * 64 + threadIdx.x] = 0;

    int row  = blockIdx.x * 4 + (threadIdx.x >> 6);
    int lane = threadIdx.x & 63;
    const float* src = (row < NB) ? (zi + (size_t)row * ND)
                                  : (zj + (size_t)(row - NB) * ND);
    float v[16];
    float s = 0.f;
#pragma unroll
    for (int seg = 0; seg < 4; ++seg) {
        float4 t = *reinterpret_cast<const float4*>(src + lane * 16 + seg * 4);
        v[seg * 4 + 0] = t.x; v[seg * 4 + 1] = t.y;
        v[seg * 4 + 2] = t.z; v[seg * 4 + 3] = t.w;
        s += t.x * t.x + t.y * t.y + t.z * t.z + t.w * t.w;
    }
#pragma unroll
    for (int off = 32; off >= 1; off >>= 1)
        s += __shfl_xor(s, off, 64);
    float inv = 127.f / fmaxf(sqrtf(s), 1e-12f);

    int4 w;
    w.x = pack4_i8(v[0]*inv,  v[1]*inv,  v[2]*inv,  v[3]*inv);
    w.y = pack4_i8(v[4]*inv,  v[5]*inv,  v[6]*inv,  v[7]*inv);
    w.z = pack4_i8(v[8]*inv,  v[9]*inv,  v[10]*inv, v[11]*inv);
    w.w = pack4_i8(v[12]*inv, v[13]*inv, v[14]*inv, v[15]*inv);

    int lc = lane >> 3;                 // logical chunk this lane-group owns
    int pc = (lc + row) & 7;            // rotated physical chunk position
    *reinterpret_cast<int4*>(pool + (size_t)row * RS + pc * 32 + (lane & 7) * 4) = w;
}

// Kernel 2: persistent, physically XCD-affine partial dots over ROTATED pool.
// 2048 co-resident blocks; each reads its real XCD id and drains its logical
// chunk's tasks in batches (one RMW per batch), then steals (peek-guarded).
// Per task: 4 rows; 32 slots (0 = positive row+NB, 1..30 = negatives, 31 =
// pad); g = lane>>3 slot-in-round, p = lane&7 16B fragment. Exact int
// partials folded into logits[row][slot] via device atomics (deterministic).
__global__ void loss_chunk_kernel(const int* __restrict__ pool,
                                  const int* __restrict__ neg_idx,
                                  int* __restrict__ logits,
                                  int* __restrict__ ctr) {
    __shared__ int task_s;
    int wave = threadIdx.x >> 6;
    int lane = threadIdx.x & 63;
    int g    = lane >> 3;
    int p    = lane & 7;
    int myx  = xcc_id();

    for (int cc = 0; cc < 8; ++cc) {
        int c = (myx + cc) & 7;

        if (cc > 0) {   // monotonic peek: skip drained chunks without an RMW
            int v = *(volatile const int*)&ctr[c * 16];
            if (v >= TPC) continue;
        }

        while (true) {
            __syncthreads();
            if (threadIdx.x == 0)
                task_s = atomicAdd(&ctr[c * 16], BATCH);
            __syncthreads();
            int t0 = task_s;
            if (t0 >= TPC) break;
            int tend = t0 + BATCH; if (tend > TPC) tend = TPC;

            for (int t = t0; t < tend; ++t) {
                int row = t * 4 + wave;

                int myidx = (lane < NK) ? neg_idx[row * NK + lane] : 0;
                int4 a4 = *reinterpret_cast<const int4*>(
                    pool + (size_t)row * RS + (((c + row) & 7) << 5) + p * 4);

                int4 b4[4];
#pragma unroll
                for (int tt = 0; tt < 4; ++tt) {
                    int s = tt * 8 + g;
                    int r = (s == 0) ? (row + NB)
                          : (s < 31) ? __shfl(myidx, s - 1, 64)
                                     : 0;          // pad slot (masked in lse)
                    b4[tt] = *reinterpret_cast<const int4*>(
                        pool + (size_t)r * RS + (((c + r) & 7) << 5) + p * 4);
                }

                int d0 = 0, d1 = 0, d2 = 0, d3 = 0;
                d0 = SDOT4(a4.x, b4[0].x, d0); d0 = SDOT4(a4.y, b4[0].y, d0);
                d0 = SDOT4(a4.z, b4[0].z, d0); d0 = SDOT4(a4.w, b4[0].w, d0);
                d1 = SDOT4(a4.x, b4[1].x, d1); d1 = SDOT4(a4.y, b4[1].y, d1);
                d1 = SDOT4(a4.z, b4[1].z, d1); d1 = SDOT4(a4.w, b4[1].w, d1);
                d2 = SDOT4(a4.x, b4[2].x, d2); d2 = SDOT4(a4.y, b4[2].y, d2);
                d2 = SDOT4(a4.z, b4[2].z, d2); d2 = SDOT4(a4.w, b4[2].w, d2);
                d3 = SDOT4(a4.x, b4[3].x, d3); d3 = SDOT4(a4.y, b4[3].y, d3);
                d3 = SDOT4(a4.z, b4[3].z, d3); d3 = SDOT4(a4.w, b4[3].w, d3);

#pragma unroll
                for (int off = 1; off <= 4; off <<= 1) {
                    d0 += __shfl_xor(d0, off, 64);
                    d1 += __shfl_xor(d1, off, 64);
                    d2 += __shfl_xor(d2, off, 64);
                    d3 += __shfl_xor(d3, off, 64);
                }

                if (p < 4) {
                    int val = (p == 0) ? d0 : (p == 1) ? d1 : (p == 2) ? d2 : d3;
                    atomicAdd(&logits[row * 32 + p * 8 + g], val);
                }
            }
        }
    }
}

// Kernel 3: logsumexp + final mean fold. 2 rows per wave, 8 rows per block.
__global__ void lse_kernel(const int* __restrict__ logits,
                           const float* __restrict__ temp_ptr,
                           float* __restrict__ out) {
    int wave = threadIdx.x >> 6;
    int lane = threadIdx.x & 63;
    int slot = lane & 31;
    int row  = blockIdx.x * 8 + wave * 2 + (lane >> 5);

    float inv_t = 1.f / (127.f * 127.f * temp_ptr[0]);

    float l = (slot < 31) ? logits[row * 32 + slot] * inv_t : -1e30f;

    float m = l;
#pragma unroll
    for (int off = 1; off <= 16; off <<= 1)
        m = fmaxf(m, __shfl_xor(m, off, 64));
    float e = __expf(l - m);
#pragma unroll
    for (int off = 1; off <= 16; off <<= 1)
        e += __shfl_xor(e, off, 64);

    float l0    = __shfl(l, lane & 32, 64);     // slot 0 of own half
    float loss  = (m + logf(e)) - l0;
    float loss2 = __shfl(loss, 32, 64);         // other half's loss

    __shared__ float red[4];
    if (lane == 0) red[wave] = loss + loss2;
    __syncthreads();
    if (threadIdx.x == 0)
        atomicAdd(out, (red[0] + red[1] + red[2] + red[3]) * (1.f / (float)NB));
}

// ---------------------------------------------------------------------------
// f32 fallback (only if ws too small for pool + logits + counters)
// ---------------------------------------------------------------------------
__global__ void norms_kernel(const float* __restrict__ zi,
                             const float* __restrict__ zj,
                             float* __restrict__ inv_norm) {
    int row  = blockIdx.x * 4 + (threadIdx.x >> 6);
    int lane = threadIdx.x & 63;
    if (row >= 2 * NB) return;
    const float* src = (row < NB) ? (zi + (size_t)row * ND)
                                  : (zj + (size_t)(row - NB) * ND);
    float s = 0.f;
#pragma unroll
    for (int seg = 0; seg < 4; ++seg) {
        float4 v = *reinterpret_cast<const float4*>(src + seg * 256 + lane * 4);
        s += v.x*v.x + v.y*v.y + v.z*v.z + v.w*v.w;
    }
#pragma unroll
    for (int off = 32; off >= 1; off >>= 1)
        s += __shfl_xor(s, off, 64);
    if (lane == 0)
        inv_norm[row] = 1.f / fmaxf(sqrtf(s), 1e-12f);
}

__global__ void loss_kernel_f32(const float* __restrict__ zi,
                                const float* __restrict__ zj,
                                const int*   __restrict__ neg_idx,
                                const float* __restrict__ temp_ptr,
                                const float* __restrict__ inv_norm,
                                float* __restrict__ partial) {
    int wave = threadIdx.x >> 6;
    int lane = threadIdx.x & 63;
    int row  = blockIdx.x * 4 + wave;
    float inv_t = 1.f / temp_ptr[0];
    const float* a = zi + (size_t)row * ND;
    float4 av[4];
#pragma unroll
    for (int seg = 0; seg < 4; ++seg)
        av[seg] = *reinterpret_cast<const float4*>(a + seg * 256 + lane * 4);
    float inv_a = inv_norm[row];
    float m = -INFINITY, ssum = 0.f, logit0 = 0.f;
    for (int k = -1; k < NK; ++k) {
        int r = (k < 0) ? (row + NB) : neg_idx[row * NK + k];
        const float* bp = (r < NB) ? (zi + (size_t)r * ND)
                                   : (zj + (size_t)(r - NB) * ND);
        float inv_b = inv_norm[r];
        float dot = 0.f;
#pragma unroll
        for (int seg = 0; seg < 4; ++seg) {
            float4 bv = *reinterpret_cast<const float4*>(bp + seg * 256 + lane * 4);
            dot += av[seg].x*bv.x + av[seg].y*bv.y + av[seg].z*bv.z + av[seg].w*bv.w;
        }
#pragma unroll
        for (int off = 32; off >= 1; off >>= 1)
            dot += __shfl_xor(dot, off, 64);
        float logit = dot * inv_a * inv_b * inv_t;
        if (k < 0) logit0 = logit;
        if (logit > m) { ssum = ssum * __expf(m - logit) + 1.f; m = logit; }
        else           { ssum += __expf(logit - m); }
    }
    float loss = (m + logf(ssum)) - logit0;
    __shared__ float red[4];
    if (lane == 0) red[wave] = loss;
    __syncthreads();
    if (threadIdx.x == 0)
        partial[blockIdx.x] = red[0] + red[1] + red[2] + red[3];
}

__global__ void reduce_kernel(const float* __restrict__ partial, int n,
                              float* __restrict__ out) {
    float s = 0.f;
    for (int i = threadIdx.x; i < n; i += 256) s += partial[i];
#pragma unroll
    for (int off = 32; off >= 1; off >>= 1)
        s += __shfl_xor(s, off, 64);
    __shared__ float lds[4];
    int wave = threadIdx.x >> 6, lane = threadIdx.x & 63;
    if (lane == 0) lds[wave] = s;
    __syncthreads();
    if (threadIdx.x == 0)
        out[0] = (lds[0] + lds[1] + lds[2] + lds[3]) * (1.f / (float)NB);
}

extern "C" void kernel_launch(void* const* d_in, const int* in_sizes, int n_in,
                              void* d_out, int out_size, void* d_ws, size_t ws_size,
                              hipStream_t stream) {
    const float* zi      = (const float*)d_in[0];
    const float* zj      = (const float*)d_in[1];
    const float* temp    = (const float*)d_in[2];
    const int*   neg_idx = (const int*)d_in[3];
    float* out = (float*)d_out;

    const size_t pool_bytes   = (size_t)2 * NB * ND;                // 16 MiB
    const size_t logits_bytes = (size_t)NB * 32 * sizeof(int);      //  1 MiB
    const size_t ctr_bytes    = 128 * sizeof(int);                  // 8 ctrs, padded

    if (ws_size >= pool_bytes + logits_bytes + ctr_bytes) {
        int* pool   = (int*)d_ws;
        int* logits = (int*)((char*)d_ws + pool_bytes);
        int* ctr    = (int*)((char*)d_ws + pool_bytes + logits_bytes);

        normalize_i8_kernel<<<(2 * NB) / 4, 256, 0, stream>>>(zi, zj, pool,
                                                              logits, ctr, out);
        loss_chunk_kernel<<<2048, 256, 0, stream>>>(pool, neg_idx, logits, ctr);
        lse_kernel<<<NB / 8, 256, 0, stream>>>(logits, temp, out);
    } else {
        float* inv_norm = (float*)d_ws;
        float* partial  = inv_norm + 2 * NB;

        norms_kernel<<<(2 * NB) / 4, 256, 0, stream>>>(zi, zj, inv_norm);
        loss_kernel_f32<<<NB / 4, 256, 0, stream>>>(zi, zj, neg_idx, temp,
                                                    inv_norm, partial);
        reduce_kernel<<<1, 256, 0, stream>>>(partial, NB / 4, out);
    }
}

// Round 15
// 40.589 us; speedup vs baseline: 2.9366x; 2.6981x over previous
//
#include <hip/hip_runtime.h>
#include <math.h>

constexpr int NB = 8192;   // batch
constexpr int ND = 1024;   // dim
constexpr int NK = 30;     // negatives
constexpr int RS = ND / 4; // row stride in ints (256)

#if defined(__has_builtin)
#  if __has_builtin(__builtin_amdgcn_sdot4)
#    define HAVE_SDOT4 1
#  endif
#endif
#ifndef HAVE_SDOT4
#  define HAVE_SDOT4 0
#endif

__device__ __forceinline__ int SDOT4(int a, int b, int acc) {
#if HAVE_SDOT4
    return __builtin_amdgcn_sdot4(a, b, acc, false);
#else
    return acc + (int)(signed char)(a)        * (int)(signed char)(b)
               + (int)(signed char)(a >> 8)   * (int)(signed char)(b >> 8)
               + (int)(signed char)(a >> 16)  * (int)(signed char)(b >> 16)
               + (int)(a >> 24)               * (int)(b >> 24);
#endif
}

__device__ __forceinline__ int pack4_i8(float a, float b, float c, float d) {
    int x0 = (int)rintf(a), x1 = (int)rintf(b), x2 = (int)rintf(c), x3 = (int)rintf(d);
    return (x0 & 255) | ((x1 & 255) << 8) | ((x2 & 255) << 16) | (x3 << 24);
}

// ---------------------------------------------------------------------------
// Kernel 1: normalize rows of [z_i; z_j] -> int8 pool [2B, D], scale 127.
// Also zero-inits the logits accumulator (stream-ordered before atomics).
// One wave per row, 4 waves/block.
// ---------------------------------------------------------------------------
__global__ void normalize_i8_kernel(const float* __restrict__ zi,
                                    const float* __restrict__ zj,
                                    int* __restrict__ pool,
                                    int* __restrict__ logits) {
    if (threadIdx.x < 64)
        logits[blockIdx.x * 64 + threadIdx.x] = 0;

    int row  = blockIdx.x * 4 + (threadIdx.x >> 6);
    int lane = threadIdx.x & 63;
    const float* src = (row < NB) ? (zi + (size_t)row * ND)
                                  : (zj + (size_t)(row - NB) * ND);
    float v[16];
    float s = 0.f;
#pragma unroll
    for (int seg = 0; seg < 4; ++seg) {
        float4 t = *reinterpret_cast<const float4*>(src + lane * 16 + seg * 4);
        v[seg * 4 + 0] = t.x; v[seg * 4 + 1] = t.y;
        v[seg * 4 + 2] = t.z; v[seg * 4 + 3] = t.w;
        s += t.x * t.x + t.y * t.y + t.z * t.z + t.w * t.w;
    }
#pragma unroll
    for (int off = 32; off >= 1; off >>= 1)
        s += __shfl_xor(s, off, 64);
    float inv = 127.f / fmaxf(sqrtf(s), 1e-12f);

    int4 w;
    w.x = pack4_i8(v[0]*inv,  v[1]*inv,  v[2]*inv,  v[3]*inv);
    w.y = pack4_i8(v[4]*inv,  v[5]*inv,  v[6]*inv,  v[7]*inv);
    w.z = pack4_i8(v[8]*inv,  v[9]*inv,  v[10]*inv, v[11]*inv);
    w.w = pack4_i8(v[12]*inv, v[13]*inv, v[14]*inv, v[15]*inv);
    *reinterpret_cast<int4*>(pool + (size_t)row * RS + lane * 4) = w;
}

// ---------------------------------------------------------------------------
// Kernel 2: XCD-sliced partial dots, folded via device-scope int atomics.
// chunk c = blockIdx.x & 7 (round-robin dispatch => chunk c tends to stay on
// XCD c, 2 MB pool slice L2-resident). 32 slots: 0 = positive (row+NB),
// 1..30 = negatives, 31 = pad. g = lane>>3 slot-in-round, p = lane&7 16B
// fragment of the 128B chunk. Exact int partials -> logits[row][slot].
// ---------------------------------------------------------------------------
__global__ void loss_chunk_kernel(const int* __restrict__ pool,
                                  const int* __restrict__ neg_idx,
                                  int* __restrict__ logits) {
    int wave = threadIdx.x >> 6;
    int lane = threadIdx.x & 63;
    int c    = blockIdx.x & 7;
    int row  = (blockIdx.x >> 3) * 4 + wave;
    int g    = lane >> 3;
    int p    = lane & 7;

    // index load heads the gather dependency chain
    int myidx = (lane < NK) ? neg_idx[row * NK + lane] : 0;

    const int* cbase = pool + c * 32 + p * 4;
    int4 a4 = *reinterpret_cast<const int4*>(cbase + (size_t)row * RS);

    // gather 4 targets (slots g, 8+g, 16+g, 24+g)
    int4 b4[4];
#pragma unroll
    for (int t = 0; t < 4; ++t) {
        int s = t * 8 + g;
        int r = (s == 0) ? (row + NB)
              : (s < 31) ? __shfl(myidx, s - 1, 64)
                         : 0;                       // pad slot (masked in lse)
        b4[t] = *reinterpret_cast<const int4*>(cbase + (size_t)r * RS);
    }

    int d0 = 0, d1 = 0, d2 = 0, d3 = 0;
    d0 = SDOT4(a4.x, b4[0].x, d0); d0 = SDOT4(a4.y, b4[0].y, d0);
    d0 = SDOT4(a4.z, b4[0].z, d0); d0 = SDOT4(a4.w, b4[0].w, d0);
    d1 = SDOT4(a4.x, b4[1].x, d1); d1 = SDOT4(a4.y, b4[1].y, d1);
    d1 = SDOT4(a4.z, b4[1].z, d1); d1 = SDOT4(a4.w, b4[1].w, d1);
    d2 = SDOT4(a4.x, b4[2].x, d2); d2 = SDOT4(a4.y, b4[2].y, d2);
    d2 = SDOT4(a4.z, b4[2].z, d2); d2 = SDOT4(a4.w, b4[2].w, d2);
    d3 = SDOT4(a4.x, b4[3].x, d3); d3 = SDOT4(a4.y, b4[3].y, d3);
    d3 = SDOT4(a4.z, b4[3].z, d3); d3 = SDOT4(a4.w, b4[3].w, d3);

    // reduce the 8 fragment-lanes of each slot (exact int adds)
#pragma unroll
    for (int off = 1; off <= 4; off <<= 1) {
        d0 += __shfl_xor(d0, off, 64);
        d1 += __shfl_xor(d1, off, 64);
        d2 += __shfl_xor(d2, off, 64);
        d3 += __shfl_xor(d3, off, 64);
    }

    // fold chunks: device-scope int atomic (associative -> deterministic)
    if (p < 4) {
        int val = (p == 0) ? d0 : (p == 1) ? d1 : (p == 2) ? d2 : d3;
        atomicAdd(&logits[row * 32 + p * 8 + g], val);
    }
}

// ---------------------------------------------------------------------------
// Kernel 3: logsumexp. 2 rows per wave (32 lanes each), 8 rows per block.
// ---------------------------------------------------------------------------
__global__ void lse_kernel(const int* __restrict__ logits,
                           const float* __restrict__ temp_ptr,
                           float* __restrict__ block_part) {
    int wave = threadIdx.x >> 6;
    int lane = threadIdx.x & 63;
    int slot = lane & 31;
    int row  = blockIdx.x * 8 + wave * 2 + (lane >> 5);

    float inv_t = 1.f / (127.f * 127.f * temp_ptr[0]);

    float l = (slot < 31) ? logits[row * 32 + slot] * inv_t : -1e30f;

    float m = l;
#pragma unroll
    for (int off = 1; off <= 16; off <<= 1)
        m = fmaxf(m, __shfl_xor(m, off, 64));
    float e = __expf(l - m);
#pragma unroll
    for (int off = 1; off <= 16; off <<= 1)
        e += __shfl_xor(e, off, 64);

    float l0    = __shfl(l, lane & 32, 64);     // slot 0 of own half
    float loss  = (m + logf(e)) - l0;
    float loss2 = __shfl(loss, 32, 64);         // other half's loss

    __shared__ float red[4];
    if (lane == 0) red[wave] = loss + loss2;
    __syncthreads();
    if (threadIdx.x == 0)
        block_part[blockIdx.x] = red[0] + red[1] + red[2] + red[3];
}

// ---------------------------------------------------------------------------
// Kernel 4: final reduction of per-block partials -> mean loss
// ---------------------------------------------------------------------------
__global__ void reduce_kernel(const float* __restrict__ partial, int n,
                              float* __restrict__ out) {
    float s = 0.f;
    for (int i = threadIdx.x; i < n; i += 256) s += partial[i];
#pragma unroll
    for (int off = 32; off >= 1; off >>= 1)
        s += __shfl_xor(s, off, 64);
    __shared__ float lds[4];
    int wave = threadIdx.x >> 6, lane = threadIdx.x & 63;
    if (lane == 0) lds[wave] = s;
    __syncthreads();
    if (threadIdx.x == 0)
        out[0] = (lds[0] + lds[1] + lds[2] + lds[3]) * (1.f / (float)NB);
}

// ---------------------------------------------------------------------------
// f32 fallback (only if ws too small for pool + logits)
// ---------------------------------------------------------------------------
__global__ void norms_kernel(const float* __restrict__ zi,
                             const float* __restrict__ zj,
                             float* __restrict__ inv_norm) {
    int row  = blockIdx.x * 4 + (threadIdx.x >> 6);
    int lane = threadIdx.x & 63;
    if (row >= 2 * NB) return;
    const float* src = (row < NB) ? (zi + (size_t)row * ND)
                                  : (zj + (size_t)(row - NB) * ND);
    float s = 0.f;
#pragma unroll
    for (int seg = 0; seg < 4; ++seg) {
        float4 v = *reinterpret_cast<const float4*>(src + seg * 256 + lane * 4);
        s += v.x*v.x + v.y*v.y + v.z*v.z + v.w*v.w;
    }
#pragma unroll
    for (int off = 32; off >= 1; off >>= 1)
        s += __shfl_xor(s, off, 64);
    if (lane == 0)
        inv_norm[row] = 1.f / fmaxf(sqrtf(s), 1e-12f);
}

__global__ void loss_kernel_f32(const float* __restrict__ zi,
                                const float* __restrict__ zj,
                                const int*   __restrict__ neg_idx,
                                const float* __restrict__ temp_ptr,
                                const float* __restrict__ inv_norm,
                                float* __restrict__ partial) {
    int wave = threadIdx.x >> 6;
    int lane = threadIdx.x & 63;
    int row  = blockIdx.x * 4 + wave;
    float inv_t = 1.f / temp_ptr[0];
    const float* a = zi + (size_t)row * ND;
    float4 av[4];
#pragma unroll
    for (int seg = 0; seg < 4; ++seg)
        av[seg] = *reinterpret_cast<const float4*>(a + seg * 256 + lane * 4);
    float inv_a = inv_norm[row];
    float m = -INFINITY, ssum = 0.f, logit0 = 0.f;
    for (int k = -1; k < NK; ++k) {
        int r = (k < 0) ? (row + NB) : neg_idx[row * NK + k];
        const float* bp = (r < NB) ? (zi + (size_t)r * ND)
                                   : (zj + (size_t)(r - NB) * ND);
        float inv_b = inv_norm[r];
        float dot = 0.f;
#pragma unroll
        for (int seg = 0; seg < 4; ++seg) {
            float4 bv = *reinterpret_cast<const float4*>(bp + seg * 256 + lane * 4);
            dot += av[seg].x*bv.x + av[seg].y*bv.y + av[seg].z*bv.z + av[seg].w*bv.w;
        }
#pragma unroll
        for (int off = 32; off >= 1; off >>= 1)
            dot += __shfl_xor(dot, off, 64);
        float logit = dot * inv_a * inv_b * inv_t;
        if (k < 0) logit0 = logit;
        if (logit > m) { ssum = ssum * __expf(m - logit) + 1.f; m = logit; }
        else           { ssum += __expf(logit - m); }
    }
    float loss = (m + logf(ssum)) - logit0;
    __shared__ float red[4];
    if (lane == 0) red[wave] = loss;
    __syncthreads();
    if (threadIdx.x == 0)
        partial[blockIdx.x] = red[0] + red[1] + red[2] + red[3];
}

extern "C" void kernel_launch(void* const* d_in, const int* in_sizes, int n_in,
                              void* d_out, int out_size, void* d_ws, size_t ws_size,
                              hipStream_t stream) {
    const float* zi      = (const float*)d_in[0];
    const float* zj      = (const float*)d_in[1];
    const float* temp    = (const float*)d_in[2];
    const int*   neg_idx = (const int*)d_in[3];
    float* out = (float*)d_out;

    const size_t pool_bytes   = (size_t)2 * NB * ND;                // 16 MiB
    const size_t logits_bytes = (size_t)NB * 32 * sizeof(int);      //  1 MiB
    const size_t block_bytes  = (size_t)(NB / 8) * sizeof(float);

    if (ws_size >= pool_bytes + logits_bytes + block_bytes) {
        int*   pool       = (int*)d_ws;
        int*   logits     = (int*)((char*)d_ws + pool_bytes);
        float* block_part = (float*)((char*)d_ws + pool_bytes + logits_bytes);

        normalize_i8_kernel<<<(2 * NB) / 4, 256, 0, stream>>>(zi, zj, pool, logits);
        loss_chunk_kernel<<<(NB / 4) * 8, 256, 0, stream>>>(pool, neg_idx, logits);
        lse_kernel<<<NB / 8, 256, 0, stream>>>(logits, temp, block_part);
        reduce_kernel<<<1, 256, 0, stream>>>(block_part, NB / 8, out);
    } else {
        float* inv_norm = (float*)d_ws;
        float* partial  = inv_norm + 2 * NB;

        norms_kernel<<<(2 * NB) / 4, 256, 0, stream>>>(zi, zj, inv_norm);
        loss_kernel_f32<<<NB / 4, 256, 0, stream>>>(zi, zj, neg_idx, temp,
                                                    inv_norm, partial);
        reduce_kernel<<<1, 256, 0, stream>>>(partial, NB / 4, out);
    }
}